// Round 19
// baseline (192.056 us; speedup 1.0000x reference)
//
#include <hip/hip_runtime.h>

// etp: out[n, coff(l3)+m3, u] = sum_p sum_{m1,m2} cg_p[m1,m2,m3] * Y[n, yoff(l1)+m1]
//                               * H[n, coff(l2)+m2, u] * W[n, p, u]
// N=16384 edges, 16 ch (l=0..3, dims 1,3,5,7), MUL=128.
//
// R18: one wave per edge, TWO scalar u-streams per lane (u=l and u=l+64).
// Halves wave count, total LDS issue (each packed-B b128 read feeds both
// streams), and total VMEM instructions vs the R13/R17 champions.
// R16's version of this spilled catastrophically because (256,6) caps VGPR
// at 85 < the ~95-reg dual live set, and it pinned 79 values at once.
// Fixes: __launch_bounds__(256,4) = 128-VGPR cap; h0/h1 pinned upfront
// (R13-proven); w pinned per l2-group only (<=14 live); packed-B layout
// (R17, conflict-free); scalar regs only (no f2/f4 allocator traps).

#define BS 256
#define EPB 4     // edges per block, one wave each
#define YD 16
#define HD 2048
#define WD 2944
#define BTOT 484  // packed B floats per edge (16B-aligned)

typedef float f4 __attribute__((ext_vector_type(4)));

__host__ __device__ constexpr int coff(int l) {
  return l == 0 ? 0 : (l == 1 ? 1 : (l == 2 ? 4 : 9));
}

// X(p, l1, l2, l3, cg_offset, flat_base)
#define FOR_PATHS(X) \
  X(0, 0,0,0,    0,   0) \
  X(1, 0,1,1,    1,  24) \
  X(2, 0,2,2,   10, 108) \
  X(3, 0,3,3,   35, 276) \
  X(4, 1,0,1,   84,   4) \
  X(5, 1,1,0,   93,  36) \
  X(6, 1,1,2,  102,  40) \
  X(7, 1,2,1,  147, 136) \
  X(8, 1,2,3,  192, 152) \
  X(9, 1,3,2,  297, 328) \
  X(10,2,0,2,  402,   8) \
  X(11,2,1,1,  427,  56) \
  X(12,2,1,3,  472,  68) \
  X(13,2,2,0,  577, 188) \
  X(14,2,2,2,  602, 196) \
  X(15,2,3,1,  727, 364) \
  X(16,2,3,3,  832, 388) \
  X(17,3,0,3, 1077,  16) \
  X(18,3,1,2, 1126,  92) \
  X(19,3,2,1, 1231, 224) \
  X(20,3,2,3, 1336, 240) \
  X(21,3,3,0, 1581, 440) \
  X(22,3,3,2, 1630, 448)

// Consume one path for both streams. B flat at Bg[BO..], chunked b128.
template <int D2, int D3, int BO, int C3>
__device__ __forceinline__ void dopath(const float* __restrict__ Bg,
                                       const float* __restrict__ h0,
                                       const float* __restrict__ h1,
                                       float wv0, float wv1,
                                       float (&acc0)[YD], float (&acc1)[YD]) {
  float s0[D3], s1[D3];
#pragma unroll
  for (int m3 = 0; m3 < D3; ++m3) { s0[m3] = 0.f; s1[m3] = 0.f; }
  f4 c;
#pragma unroll
  for (int f = 0; f < D2 * D3; ++f) {
    if ((f & 3) == 0) c = *(const f4*)(Bg + BO + f);
    const float b = c[f & 3];
    s0[f / D2] += b * h0[f % D2];
    s1[f / D2] += b * h1[f % D2];
  }
#pragma unroll
  for (int m3 = 0; m3 < D3; ++m3) {
    acc0[C3 + m3] += s0[m3] * wv0;
    acc1[C3 + m3] += s1[m3] * wv1;
  }
}

__global__ __launch_bounds__(BS, 4) void etp_kernel(
    const float* __restrict__ Y, const float* __restrict__ H,
    const float* __restrict__ W, const float* __restrict__ CG,
    float* __restrict__ O) {
  const int g = threadIdx.x >> 6;   // edge within block (one wave each)
  const int l = threadIdx.x & 63;   // lane; owns u = l and u = l+64
  const size_t n = (size_t)blockIdx.x * EPB + g;

  __shared__ __align__(16) float Bsm[EPB][BTOT];  // 7744 B
  __shared__ float ysm[EPB][YD];

  { const int t = threadIdx.x;
    if (t < EPB * YD) {
      const int e = t >> 4, c = t & 15;
      ysm[e][c] = Y[(size_t)(blockIdx.x * EPB + e) * YD + c];
    } }
  __syncthreads();

  // Phase 1: B flat-packed: lane l (= m3*d2+m2 row-major) writes B[BO+l].
#define BUILD(P, L1, L2, L3, CGO, BO) { \
    constexpr int d1 = 2*(L1)+1, d2 = 2*(L2)+1, d3 = 2*(L3)+1; \
    if (l < d2 * d3) { \
      const int m3 = l / d2, m2 = l - m3 * d2; \
      float s = 0.f; \
      _Pragma("unroll") \
      for (int a = 0; a < d1; ++a) \
        s += CG[(CGO) + (a * d2 + m2) * d3 + m3] * ysm[g][coff(L1) + a]; \
      Bsm[g][(BO) + l] = s; \
    } }
  FOR_PATHS(BUILD)
#undef BUILD
  __syncthreads();

  // Phase 2: dual scalar streams. h upfront+pinned; w per l2-group.
  const float* __restrict__ Hn = H + n * HD + l;
  const float* __restrict__ Wn = W + n * WD + l;
  float* __restrict__ On = O + n * HD + l;
  const float* __restrict__ Bg = &Bsm[g][0];

  float h0[YD], h1[YD];
#pragma unroll
  for (int c = 0; c < YD; ++c) {
    h0[c] = Hn[c * 128];
    h1[c] = Hn[c * 128 + 64];
  }
#pragma unroll
  for (int c = 0; c < YD; ++c) {
    asm volatile("" : "+v"(h0[c]));
    asm volatile("" : "+v"(h1[c]));
  }

  float acc0[YD], acc1[YD];
#pragma unroll
  for (int c = 0; c < YD; ++c) { acc0[c] = 0.f; acc1[c] = 0.f; }

#define DOP(P, L2, L3, BO, WI) \
  dopath<2*(L2)+1, 2*(L3)+1, BO, coff(L3)>(Bg, &h0[coff(L2)], &h1[coff(L2)], \
                                           wg0[WI], wg1[WI], acc0, acc1);

  { // l2=0: paths 0,4,10,17
    float wg0[4], wg1[4];
    const int pid[4] = {0, 4, 10, 17};
#pragma unroll
    for (int i = 0; i < 4; ++i) {
      wg0[i] = Wn[pid[i] * 128]; wg1[i] = Wn[pid[i] * 128 + 64];
    }
#pragma unroll
    for (int i = 0; i < 4; ++i) {
      asm volatile("" : "+v"(wg0[i])); asm volatile("" : "+v"(wg1[i]));
    }
    DOP(0, 0, 0, 0, 0)  DOP(4, 0, 1, 4, 1)
    DOP(10, 0, 2, 8, 2) DOP(17, 0, 3, 16, 3)
  }
  { // l2=1: paths 1,5,6,11,12,18
    float wg0[6], wg1[6];
    const int pid[6] = {1, 5, 6, 11, 12, 18};
#pragma unroll
    for (int i = 0; i < 6; ++i) {
      wg0[i] = Wn[pid[i] * 128]; wg1[i] = Wn[pid[i] * 128 + 64];
    }
#pragma unroll
    for (int i = 0; i < 6; ++i) {
      asm volatile("" : "+v"(wg0[i])); asm volatile("" : "+v"(wg1[i]));
    }
    DOP(1, 1, 1, 24, 0)   DOP(5, 1, 0, 36, 1)  DOP(6, 1, 2, 40, 2)
    DOP(11, 1, 1, 56, 3)  DOP(12, 1, 3, 68, 4) DOP(18, 1, 2, 92, 5)
  }
  { // l2=2: paths 2,7,8,13,14,19,20
    float wg0[7], wg1[7];
    const int pid[7] = {2, 7, 8, 13, 14, 19, 20};
#pragma unroll
    for (int i = 0; i < 7; ++i) {
      wg0[i] = Wn[pid[i] * 128]; wg1[i] = Wn[pid[i] * 128 + 64];
    }
#pragma unroll
    for (int i = 0; i < 7; ++i) {
      asm volatile("" : "+v"(wg0[i])); asm volatile("" : "+v"(wg1[i]));
    }
    DOP(2, 2, 2, 108, 0)   DOP(7, 2, 1, 136, 1)  DOP(8, 2, 3, 152, 2)
    DOP(13, 2, 0, 188, 3)  DOP(14, 2, 2, 196, 4) DOP(19, 2, 1, 224, 5)
    DOP(20, 2, 3, 240, 6)
  }
  { // l2=3: paths 3,9,15,16,21,22
    float wg0[6], wg1[6];
    const int pid[6] = {3, 9, 15, 16, 21, 22};
#pragma unroll
    for (int i = 0; i < 6; ++i) {
      wg0[i] = Wn[pid[i] * 128]; wg1[i] = Wn[pid[i] * 128 + 64];
    }
#pragma unroll
    for (int i = 0; i < 6; ++i) {
      asm volatile("" : "+v"(wg0[i])); asm volatile("" : "+v"(wg1[i]));
    }
    DOP(3, 3, 3, 276, 0)   DOP(9, 3, 2, 328, 1)  DOP(15, 3, 1, 364, 2)
    DOP(16, 3, 3, 388, 3)  DOP(21, 3, 0, 440, 4) DOP(22, 3, 2, 448, 5)
  }
#undef DOP

#pragma unroll
  for (int c = 0; c < YD; ++c) {
    __builtin_nontemporal_store(acc0[c], &On[c * 128]);
    __builtin_nontemporal_store(acc1[c], &On[c * 128 + 64]);
  }
}

extern "C" void kernel_launch(void* const* d_in, const int* in_sizes, int n_in,
                              void* d_out, int out_size, void* d_ws, size_t ws_size,
                              hipStream_t stream) {
  const float* Y  = (const float*)d_in[0];
  const float* H  = (const float*)d_in[1];
  const float* W  = (const float*)d_in[2];
  const float* CG = (const float*)d_in[3];
  float* O = (float*)d_out;

  const int n_edges = in_sizes[0] / YD;        // 16384
  etp_kernel<<<n_edges / EPB, BS, 0, stream>>>(Y, H, W, CG, O);
}

// Round 20
// 101.681 us; speedup vs baseline: 1.8888x; 1.8888x over previous
//
#include <hip/hip_runtime.h>

// etp: out[n, coff(l3)+m3, u] = sum_p sum_{m1,m2} cg_p[m1,m2,m3] * Y[n, yoff(l1)+m1]
//                               * H[n, coff(l2)+m2, u] * W[n, p, u]
// N=16384 edges, 16 ch (l=0..3, dims 1,3,5,7), MUL=128.
//
// R19 = R13 champion (95.1us: scalar u, 128 thr/edge, 2 edges/block,
// upfront 39-load burst with sequential pins, nt stores) with
// __launch_bounds__(256,8): R13's VGPR=36 and 6.7KB LDS permit 8 waves/EU,
// but (256,6) left it at 69% occupancy. Pure occupancy lever, zero
// structural risk. R18's dual-stream spilled (VGPR allocator pins at 64,
// 387MB scratch) — family abandoned.
// 19-round ledger: every clean structure lands 95-110us; blended
// L3+HBM delivery ~4.3-4.7 TB/s over the 444MB working set = 94-103us.

#define BS 256
#define EPB 2     // edges per block
#define TPE 128   // threads per edge
#define YD 16
#define HD 2048
#define WD 2944
#define NP 23
#define NROW 99   // sum of d3 over paths (B rows, padded to 8 floats)

typedef float f4 __attribute__((ext_vector_type(4)));

// X(p, l1, l2, l3, cg_offset, row_offset)
#define FOR_PATHS(X) \
  X(0, 0,0,0,    0,  0) \
  X(1, 0,1,1,    1,  1) \
  X(2, 0,2,2,   10,  4) \
  X(3, 0,3,3,   35,  9) \
  X(4, 1,0,1,   84, 16) \
  X(5, 1,1,0,   93, 19) \
  X(6, 1,1,2,  102, 20) \
  X(7, 1,2,1,  147, 25) \
  X(8, 1,2,3,  192, 28) \
  X(9, 1,3,2,  297, 35) \
  X(10,2,0,2,  402, 40) \
  X(11,2,1,1,  427, 45) \
  X(12,2,1,3,  472, 48) \
  X(13,2,2,0,  577, 55) \
  X(14,2,2,2,  602, 56) \
  X(15,2,3,1,  727, 61) \
  X(16,2,3,3,  832, 64) \
  X(17,3,0,3, 1077, 71) \
  X(18,3,1,2, 1126, 78) \
  X(19,3,2,1, 1231, 83) \
  X(20,3,2,3, 1336, 86) \
  X(21,3,3,0, 1581, 93) \
  X(22,3,3,2, 1630, 94)

__host__ __device__ constexpr int coff(int l) {
  return l == 0 ? 0 : (l == 1 ? 1 : (l == 2 ? 4 : 9));
}

__global__ __launch_bounds__(BS, 8) void etp_kernel(
    const float* __restrict__ Y, const float* __restrict__ H,
    const float* __restrict__ W, const float* __restrict__ CG,
    float* __restrict__ O) {
  const int g = threadIdx.x >> 7;    // edge within block
  const int u = threadIdx.x & 127;   // u index
  const size_t n = (size_t)blockIdx.x * EPB + g;

  __shared__ __align__(16) float Bsm[EPB][NROW * 8];  // 6336 B
  __shared__ float ysm[EPB][YD];

  { const int t = threadIdx.x;
    if (t < EPB * YD) {
      const int e = t >> 4, c = t & 15;
      ysm[e][c] = Y[(size_t)(blockIdx.x * EPB + e) * YD + c];
    } }
  __syncthreads();

  // Phase 1: B_p[m3][m2] = sum_a cg_p[a,m2,m3] * y[coff(l1)+a], per edge.
#define BUILD(P, L1, L2, L3, CGO, RO) { \
    constexpr int d1 = 2*(L1)+1, d2 = 2*(L2)+1, d3 = 2*(L3)+1; \
    if (u < d2 * d3) { \
      const int m3 = u / d2, m2 = u - m3 * d2; \
      float s = 0.f; \
      _Pragma("unroll") \
      for (int a = 0; a < d1; ++a) \
        s += CG[(CGO) + (a * d2 + m2) * d3 + m3] * ysm[g][coff(L1) + a]; \
      Bsm[g][((RO) + m3) * 8 + m2] = s; \
    } }
  FOR_PATHS(BUILD)
#undef BUILD
  __syncthreads();

  // Phase 2: one burst of ALL 39 loads (pinned), then pure reg/LDS compute.
  const float* __restrict__ Hn = H + n * HD + u;
  const float* __restrict__ Wn = W + n * WD + u;
  float* __restrict__ On = O + n * HD + u;

  float h[YD];
#pragma unroll
  for (int c = 0; c < YD; ++c) h[c] = Hn[c * TPE];
  float w[NP];
#pragma unroll
  for (int p = 0; p < NP; ++p) w[p] = Wn[p * TPE];
  // Pin: forbid rematerialization/sinking of the burst.
#pragma unroll
  for (int c = 0; c < YD; ++c) asm volatile("" : "+v"(h[c]));
#pragma unroll
  for (int p = 0; p < NP; ++p) asm volatile("" : "+v"(w[p]));

  float acc[YD];
#pragma unroll
  for (int c = 0; c < YD; ++c) acc[c] = 0.f;

#define DOP(P, L1, L2, L3, CGO, RO) { \
    constexpr int d2 = 2*(L2)+1, d3 = 2*(L3)+1; \
    const float wv = w[P]; \
    _Pragma("unroll") \
    for (int m3 = 0; m3 < d3; ++m3) { \
      const f4* row = (const f4*)&Bsm[g][((RO) + m3) * 8]; \
      float br[8]; \
      *(f4*)&br[0] = row[0]; \
      if (d2 > 4) *(f4*)&br[4] = row[1]; \
      float s = 0.f; \
      _Pragma("unroll") \
      for (int m2 = 0; m2 < d2; ++m2) s += br[m2] * h[coff(L2) + m2]; \
      acc[coff(L3) + m3] += s * wv; \
    } }
  FOR_PATHS(DOP)
#undef DOP

#pragma unroll
  for (int c = 0; c < YD; ++c)
    __builtin_nontemporal_store(acc[c], &On[c * TPE]);
}

extern "C" void kernel_launch(void* const* d_in, const int* in_sizes, int n_in,
                              void* d_out, int out_size, void* d_ws, size_t ws_size,
                              hipStream_t stream) {
  const float* Y  = (const float*)d_in[0];
  const float* H  = (const float*)d_in[1];
  const float* W  = (const float*)d_in[2];
  const float* CG = (const float*)d_in[3];
  float* O = (float*)d_out;

  const int n_edges = in_sizes[0] / YD;        // 16384
  etp_kernel<<<n_edges / EPB, BS, 0, stream>>>(Y, H, W, CG, O);
}

// Round 21
// 95.624 us; speedup vs baseline: 2.0084x; 1.0633x over previous
//
#include <hip/hip_runtime.h>

// etp: out[n, coff(l3)+m3, u] = sum_p sum_{m1,m2} cg_p[m1,m2,m3] * Y[n, yoff(l1)+m1]
//                               * H[n, coff(l2)+m2, u] * W[n, p, u]
// N=16384 edges, 16 ch (l=0..3, dims 1,3,5,7), MUL=128.
//
// R20 = R13 champion restored verbatim (95.1us measured). 21-round ledger:
// every clean structure lands 95-110us; the binding constraint is ~450MB of
// compulsory traffic through the measured ~4.6TB/s blended L3+HBM delivery
// (mixed 23-stream read + nt-write) = ~95us. R13 sits at the register/
// occupancy saddle: (256,6) = 85-VGPR budget holds the 39-value pinned
// burst without spill (R19's (256,8) -> VGPR 32 -> 16MB spill -> 101.7us;
// R18's dual-stream -> 387MB spill; f2/f4 shapes -> aligned-pair spills).
// Scalar u, 128 thr/edge, 2 edges/block; B in padded-8 LDS rows; upfront
// 39-load burst with sequential asm pins; nontemporal stores.

#define BS 256
#define EPB 2     // edges per block
#define TPE 128   // threads per edge
#define YD 16
#define HD 2048
#define WD 2944
#define NP 23
#define NROW 99   // sum of d3 over paths (B rows, padded to 8 floats)

typedef float f4 __attribute__((ext_vector_type(4)));

// X(p, l1, l2, l3, cg_offset, row_offset)
#define FOR_PATHS(X) \
  X(0, 0,0,0,    0,  0) \
  X(1, 0,1,1,    1,  1) \
  X(2, 0,2,2,   10,  4) \
  X(3, 0,3,3,   35,  9) \
  X(4, 1,0,1,   84, 16) \
  X(5, 1,1,0,   93, 19) \
  X(6, 1,1,2,  102, 20) \
  X(7, 1,2,1,  147, 25) \
  X(8, 1,2,3,  192, 28) \
  X(9, 1,3,2,  297, 35) \
  X(10,2,0,2,  402, 40) \
  X(11,2,1,1,  427, 45) \
  X(12,2,1,3,  472, 48) \
  X(13,2,2,0,  577, 55) \
  X(14,2,2,2,  602, 56) \
  X(15,2,3,1,  727, 61) \
  X(16,2,3,3,  832, 64) \
  X(17,3,0,3, 1077, 71) \
  X(18,3,1,2, 1126, 78) \
  X(19,3,2,1, 1231, 83) \
  X(20,3,2,3, 1336, 86) \
  X(21,3,3,0, 1581, 93) \
  X(22,3,3,2, 1630, 94)

__host__ __device__ constexpr int coff(int l) {
  return l == 0 ? 0 : (l == 1 ? 1 : (l == 2 ? 4 : 9));
}

__global__ __launch_bounds__(BS, 6) void etp_kernel(
    const float* __restrict__ Y, const float* __restrict__ H,
    const float* __restrict__ W, const float* __restrict__ CG,
    float* __restrict__ O) {
  const int g = threadIdx.x >> 7;    // edge within block
  const int u = threadIdx.x & 127;   // u index
  const size_t n = (size_t)blockIdx.x * EPB + g;

  __shared__ __align__(16) float Bsm[EPB][NROW * 8];  // 6336 B
  __shared__ float ysm[EPB][YD];

  { const int t = threadIdx.x;
    if (t < EPB * YD) {
      const int e = t >> 4, c = t & 15;
      ysm[e][c] = Y[(size_t)(blockIdx.x * EPB + e) * YD + c];
    } }
  __syncthreads();

  // Phase 1: B_p[m3][m2] = sum_a cg_p[a,m2,m3] * y[coff(l1)+a], per edge.
#define BUILD(P, L1, L2, L3, CGO, RO) { \
    constexpr int d1 = 2*(L1)+1, d2 = 2*(L2)+1, d3 = 2*(L3)+1; \
    if (u < d2 * d3) { \
      const int m3 = u / d2, m2 = u - m3 * d2; \
      float s = 0.f; \
      _Pragma("unroll") \
      for (int a = 0; a < d1; ++a) \
        s += CG[(CGO) + (a * d2 + m2) * d3 + m3] * ysm[g][coff(L1) + a]; \
      Bsm[g][((RO) + m3) * 8 + m2] = s; \
    } }
  FOR_PATHS(BUILD)
#undef BUILD
  __syncthreads();

  // Phase 2: one burst of ALL 39 loads (pinned), then pure reg/LDS compute.
  const float* __restrict__ Hn = H + n * HD + u;
  const float* __restrict__ Wn = W + n * WD + u;
  float* __restrict__ On = O + n * HD + u;

  float h[YD];
#pragma unroll
  for (int c = 0; c < YD; ++c) h[c] = Hn[c * TPE];
  float w[NP];
#pragma unroll
  for (int p = 0; p < NP; ++p) w[p] = Wn[p * TPE];
  // Pin: forbid rematerialization/sinking of the burst.
#pragma unroll
  for (int c = 0; c < YD; ++c) asm volatile("" : "+v"(h[c]));
#pragma unroll
  for (int p = 0; p < NP; ++p) asm volatile("" : "+v"(w[p]));

  float acc[YD];
#pragma unroll
  for (int c = 0; c < YD; ++c) acc[c] = 0.f;

#define DOP(P, L1, L2, L3, CGO, RO) { \
    constexpr int d2 = 2*(L2)+1, d3 = 2*(L3)+1; \
    const float wv = w[P]; \
    _Pragma("unroll") \
    for (int m3 = 0; m3 < d3; ++m3) { \
      const f4* row = (const f4*)&Bsm[g][((RO) + m3) * 8]; \
      float br[8]; \
      *(f4*)&br[0] = row[0]; \
      if (d2 > 4) *(f4*)&br[4] = row[1]; \
      float s = 0.f; \
      _Pragma("unroll") \
      for (int m2 = 0; m2 < d2; ++m2) s += br[m2] * h[coff(L2) + m2]; \
      acc[coff(L3) + m3] += s * wv; \
    } }
  FOR_PATHS(DOP)
#undef DOP

#pragma unroll
  for (int c = 0; c < YD; ++c)
    __builtin_nontemporal_store(acc[c], &On[c * TPE]);
}

extern "C" void kernel_launch(void* const* d_in, const int* in_sizes, int n_in,
                              void* d_out, int out_size, void* d_ws, size_t ws_size,
                              hipStream_t stream) {
  const float* Y  = (const float*)d_in[0];
  const float* H  = (const float*)d_in[1];
  const float* W  = (const float*)d_in[2];
  const float* CG = (const float*)d_in[3];
  float* O = (float*)d_out;

  const int n_edges = in_sizes[0] / YD;        // 16384
  etp_kernel<<<n_edges / EPB, BS, 0, stream>>>(Y, H, W, CG, O);
}